// Round 1
// baseline (165.027 us; speedup 1.0000x reference)
//
#include <hip/hip_runtime.h>

#define NODE_IN 64
#define EDGE_IN 32
#define GLOBAL_IN 32
#define HID 128
#define EOUT 32

typedef float f32x4 __attribute__((ext_vector_type(4)));
typedef short s16x8 __attribute__((ext_vector_type(8)));
typedef unsigned short u16x4 __attribute__((ext_vector_type(4)));

// RNE float -> bf16 (bit trick; inputs are normal floats)
__device__ __forceinline__ unsigned short f2bf(float f) {
  unsigned int u = __float_as_uint(f);
  u += 0x7FFFu + ((u >> 16) & 1u);
  return (unsigned short)(u >> 16);
}

__device__ __forceinline__ u16x4 cvt4(f32x4 v) {
  u16x4 r = { f2bf(v[0]), f2bf(v[1]), f2bf(v[2]), f2bf(v[3]) };
  return r;
}

// Block: 256 threads = 4 waves. Tile: 64 edges.
// Layer1: H[64][128] = relu(X[64][192] @ W1 + b1), X staged bf16 in LDS.
//   Wave w owns H columns [32w, 32w+32): 2 n-tiles x 6 k-tiles x 4 m-tiles MFMAs.
// Layer2: OUT[64][32] = H @ W2 + b2. Wave w owns rows [16w, 16w+16).
__global__ __launch_bounds__(256) void edge_mlp(
    const float* __restrict__ srcp, const float* __restrict__ dstp,
    const float* __restrict__ eap, const float* __restrict__ up,
    const int* __restrict__ ebp, const float* __restrict__ W1,
    const float* __restrict__ b1, const float* __restrict__ W2,
    const float* __restrict__ b2, float* __restrict__ outp,
    int E, int ntiles)
{
  // pad 192->200 (row stride 400B -> 4-dword bank skew: 2-way aliasing, free)
  __shared__ __align__(16) unsigned short Xl[64][200];
  // pad 128->136 (row stride 272B): 2-way aliasing on b128 reads
  __shared__ __align__(16) unsigned short Hl[64][136];

  const int t = threadIdx.x;
  const int wid = t >> 6;      // wave id 0..3
  const int lane = t & 63;
  const int g = lane >> 4;     // lane group 0..3
  const int r16 = lane & 15;

  // ---- preload weight fragments (once per block, L2-resident source) ----
  // B-frag layout for mfma_f32_16x16x32_bf16: lane holds B[k=8*(l>>4)+j][col=l&15]
  s16x8 w1f[6][2];
#pragma unroll
  for (int kk = 0; kk < 6; ++kk) {
#pragma unroll
    for (int nt = 0; nt < 2; ++nt) {
      s16x8 v;
#pragma unroll
      for (int j = 0; j < 8; ++j) {
        v[j] = (short)f2bf(W1[(32*kk + 8*g + j)*HID + 32*wid + 16*nt + r16]);
      }
      w1f[kk][nt] = v;
    }
  }
  s16x8 w2f[4][2];
#pragma unroll
  for (int kk = 0; kk < 4; ++kk) {
#pragma unroll
    for (int nt = 0; nt < 2; ++nt) {
      s16x8 v;
#pragma unroll
      for (int j = 0; j < 8; ++j) {
        v[j] = (short)f2bf(W2[(32*kk + 8*g + j)*EOUT + 16*nt + r16]);
      }
      w2f[kk][nt] = v;
    }
  }
  const float b1v0 = b1[32*wid + r16];
  const float b1v1 = b1[32*wid + 16 + r16];
  const float b2v0 = b2[r16];
  const float b2v1 = b2[16 + r16];

  for (int tile = blockIdx.x; tile < ntiles; tile += gridDim.x) {
    const int mbase = tile * 64;

    // ---- stage X-tile (concat of src|dest|edge_attr|u[eb]) as bf16 ----
#pragma unroll
    for (int i = 0; i < 4; ++i) {
      const int idx = t + 256*i;           // 0..1023
      const int row = idx >> 4, c4 = idx & 15;
      int grow = mbase + row; grow = grow < E ? grow : (E - 1);
      const f32x4 vs = *(const f32x4*)(srcp + (size_t)grow*NODE_IN + c4*4);
      *(u16x4*)&Xl[row][c4*4] = cvt4(vs);
      const f32x4 vd = *(const f32x4*)(dstp + (size_t)grow*NODE_IN + c4*4);
      *(u16x4*)&Xl[row][NODE_IN + c4*4] = cvt4(vd);
    }
#pragma unroll
    for (int i = 0; i < 2; ++i) {
      const int idx = t + 256*i;           // 0..511
      const int row = idx >> 3, c4 = idx & 7;
      int grow = mbase + row; grow = grow < E ? grow : (E - 1);
      const f32x4 ve = *(const f32x4*)(eap + (size_t)grow*EDGE_IN + c4*4);
      *(u16x4*)&Xl[row][2*NODE_IN + c4*4] = cvt4(ve);
      const int bb = ebp[grow];
      const f32x4 vu = *(const f32x4*)(up + (size_t)bb*GLOBAL_IN + c4*4);
      *(u16x4*)&Xl[row][2*NODE_IN + EDGE_IN + c4*4] = cvt4(vu);
    }
    __syncthreads();

    // ---- layer 1: per wave, 4 m-tiles x 2 n-tiles, K=192 ----
    f32x4 acc[4][2];
    {
      const f32x4 z = {0.f, 0.f, 0.f, 0.f};
#pragma unroll
      for (int mi = 0; mi < 4; ++mi) { acc[mi][0] = z; acc[mi][1] = z; }
    }
#pragma unroll
    for (int kk = 0; kk < 6; ++kk) {
#pragma unroll
      for (int mi = 0; mi < 4; ++mi) {
        // A-frag: lane holds X[row=l&15][k=8*(l>>4)+j] -> 8 contiguous bf16
        const s16x8 a = *(const s16x8*)&Xl[16*mi + r16][32*kk + 8*g];
        acc[mi][0] = __builtin_amdgcn_mfma_f32_16x16x32_bf16(a, w1f[kk][0], acc[mi][0], 0, 0, 0);
        acc[mi][1] = __builtin_amdgcn_mfma_f32_16x16x32_bf16(a, w1f[kk][1], acc[mi][1], 0, 0, 0);
      }
    }
    // epilogue: +b1, relu, bf16 -> Hl. D layout: row=4g+j (within m-tile), col=r16
#pragma unroll
    for (int mi = 0; mi < 4; ++mi) {
#pragma unroll
      for (int j = 0; j < 4; ++j) {
        const float h0 = fmaxf(acc[mi][0][j] + b1v0, 0.f);
        const float h1 = fmaxf(acc[mi][1][j] + b1v1, 0.f);
        Hl[16*mi + 4*g + j][32*wid + r16]      = f2bf(h0);
        Hl[16*mi + 4*g + j][32*wid + 16 + r16] = f2bf(h1);
      }
    }
    __syncthreads();

    // ---- layer 2: wave owns 16 rows, K=128, N=32 ----
    f32x4 acc2[2];
    {
      const f32x4 z = {0.f, 0.f, 0.f, 0.f};
      acc2[0] = z; acc2[1] = z;
    }
#pragma unroll
    for (int kk = 0; kk < 4; ++kk) {
      const s16x8 a = *(const s16x8*)&Hl[16*wid + r16][32*kk + 8*g];
      acc2[0] = __builtin_amdgcn_mfma_f32_16x16x32_bf16(a, w2f[kk][0], acc2[0], 0, 0, 0);
      acc2[1] = __builtin_amdgcn_mfma_f32_16x16x32_bf16(a, w2f[kk][1], acc2[1], 0, 0, 0);
    }
#pragma unroll
    for (int j = 0; j < 4; ++j) {
      const int m = mbase + 16*wid + 4*g + j;
      if (m < E) {
        outp[(size_t)m*EOUT + r16]      = acc2[0][j] + b2v0;
        outp[(size_t)m*EOUT + 16 + r16] = acc2[1][j] + b2v1;
      }
    }
    // no trailing barrier needed: next-iter stage writes Xl (not read in L2 phase);
    // next-iter Hl writes are gated by the post-stage barrier.
  }
}

extern "C" void kernel_launch(void* const* d_in, const int* in_sizes, int n_in,
                              void* d_out, int out_size, void* d_ws, size_t ws_size,
                              hipStream_t stream) {
  const float* srcp = (const float*)d_in[0];
  const float* dstp = (const float*)d_in[1];
  const float* eap  = (const float*)d_in[2];
  const float* up   = (const float*)d_in[3];
  const int*   ebp  = (const int*)d_in[4];
  const float* W1   = (const float*)d_in[5];
  const float* b1   = (const float*)d_in[6];
  const float* W2   = (const float*)d_in[7];
  const float* b2   = (const float*)d_in[8];
  float* outp = (float*)d_out;

  const int E = in_sizes[0] / NODE_IN;
  const int ntiles = (E + 63) / 64;
  const int grid = ntiles < 2048 ? ntiles : 2048;

  edge_mlp<<<grid, 256, 0, stream>>>(srcp, dstp, eap, up, ebp, W1, b1, W2, b2,
                                     outp, E, ntiles);
}